// Round 1
// baseline (9169.981 us; speedup 1.0000x reference)
//
#include <hip/hip_runtime.h>

#define B_ 128
#define T_ 256
#define F_ 128
#define H_ 768
#define NG 3072      // 4*H
#define BM 32
#define BN 64
#define BK 128
#define UPT 16       // units per N-tile = BN/4

typedef short s16x8 __attribute__((ext_vector_type(8)));
typedef float f32x4 __attribute__((ext_vector_type(4)));

__device__ __forceinline__ unsigned short f2bf(float x) {
  unsigned u = __float_as_uint(x);
  u += 0x7fffu + ((u >> 16) & 1u);
  return (unsigned short)(u >> 16);
}

__device__ __forceinline__ void async16(const void* g, void* l) {
  __builtin_amdgcn_global_load_lds(
      (const __attribute__((address_space(1))) void*)g,
      (__attribute__((address_space(3))) void*)l, 16, 0, 0);
}

struct Cell {
  const unsigned short* A1; int lda1; int K1;   // bf16 [128 x K1], row stride lda1 (elems)
  const unsigned short* A2; int lda2; int K2;   // K-concatenated second operand
  const unsigned short* W;  int ldw;            // bf16 [N x (K1+K2)], pre-permuted gate rows
  const float* bias;                            // [N] permuted
  float* c;                                     // [128 x 768] f32 state (in/out)
  unsigned short* h;                            // [128 x 768] bf16 h out
  float* yout; int yt;                          // y columns go to yout[b][yt][f]
  int N; int ngates;
};

// ---------------- main fused LSTM-cell GEMM kernel ----------------
__global__ __launch_bounds__(256) void cell_kernel(Cell ca, Cell cb, int nblk_a)
{
  __shared__ union SM {
    struct { unsigned short A[2][BM*BK]; unsigned short Bm[2][BN*BK]; } stg; // 48KB
    float gates[BM][BN+4];
  } sm;

  const bool isB = (int)blockIdx.x >= nblk_a;
  const Cell C = isB ? cb : ca;
  const int idx = isB ? ((int)blockIdx.x - nblk_a) : (int)blockIdx.x;
  const int tm = idx & 3;        // 128/32 m-tiles
  const int tn = idx >> 2;
  const int b0 = tm * BM;

  const int tid  = (int)threadIdx.x;
  const int wave = tid >> 6;
  const int lane = tid & 63;
  const int wm = wave >> 1, wn = wave & 1;

  const int nit = (C.K1 + C.K2) / BK;

  f32x4 acc[2] = {{0.f,0.f,0.f,0.f},{0.f,0.f,0.f,0.f}};

  // stage one BK=128 K-slab into LDS buffer buf via global_load_lds(16B).
  // LDS is linear; the XOR swizzle (16B-slot ^ (row&7)) is applied by
  // pre-swizzling the GLOBAL source address (m173 pattern) and on ds_read.
  auto stage = [&](int buf, int kk) {
#pragma unroll
    for (int q = 0; q < 2; ++q) {            // A: 8KB = 8 chunks of 1KB
      int cch = wave*2 + q;
      int P = cch*1024 + lane*16;
      int r = P >> 8;                        // row 0..31 (256B rows)
      int sl = ((P >> 4) & 15) ^ (r & 7);    // logical 16B slot
      int ke = kk + sl*8;
      const unsigned short* gp = (ke < C.K1)
        ? (C.A1 + (long)(b0 + r) * C.lda1 + ke)
        : (C.A2 + (long)(b0 + r) * C.lda2 + (ke - C.K1));
      async16(gp, (char*)(sm.stg.A[buf]) + cch*1024);
    }
#pragma unroll
    for (int q = 0; q < 4; ++q) {            // B: 16KB = 16 chunks
      int cch = wave*4 + q;
      int P = cch*1024 + lane*16;
      int r = P >> 8;                        // row 0..63
      int sl = ((P >> 4) & 15) ^ (r & 7);
      int ke = kk + sl*8;
      const unsigned short* gp = C.W + (long)(tn*BN + r) * C.ldw + ke;
      async16(gp, (char*)(sm.stg.Bm[buf]) + cch*1024);
    }
  };

  stage(0, 0);
  for (int it = 0; it < nit; ++it) {
    int buf = it & 1;
    __syncthreads();                          // vmcnt(0) drain + barrier: buf ready
    if (it + 1 < nit) stage(buf ^ 1, (it + 1) * BK);   // prefetch overlaps compute
    const char* At = (const char*)(sm.stg.A[buf]);
    const char* Bt = (const char*)(sm.stg.Bm[buf]);
#pragma unroll
    for (int ks = 0; ks < 4; ++ks) {
      int ar = wm*16 + (lane & 15);
      int as = (ks*4 + (lane >> 4)) ^ (ar & 7);
      s16x8 a = *(const s16x8*)(At + ar*256 + as*16);
#pragma unroll
      for (int nf = 0; nf < 2; ++nf) {
        int br = wn*32 + nf*16 + (lane & 15);
        int bsl = (ks*4 + (lane >> 4)) ^ (br & 7);
        s16x8 b = *(const s16x8*)(Bt + br*256 + bsl*16);
        acc[nf] = __builtin_amdgcn_mfma_f32_16x16x32_bf16(a, b, acc[nf], 0, 0, 0);
      }
    }
  }

  const int gcol0 = tn * BN;
  if (gcol0 >= C.ngates) {
    // pure y tile: write directly to output (f32), bias added
#pragma unroll
    for (int nf = 0; nf < 2; ++nf) {
      int col = wn*32 + nf*16 + (lane & 15);
      float bia = C.bias[gcol0 + col];
      int fo = gcol0 + col - C.ngates;
#pragma unroll
      for (int rg = 0; rg < 4; ++rg) {
        int brow = wm*16 + (lane >> 4)*4 + rg;     // D row = (lane>>4)*4+reg
        C.yout[(long)(b0 + brow)*(T_*F_) + (long)C.yt*F_ + fo] = acc[nf][rg] + bia;
      }
    }
    return;
  }

  __syncthreads();
#pragma unroll
  for (int nf = 0; nf < 2; ++nf) {
    int col = wn*32 + nf*16 + (lane & 15);
#pragma unroll
    for (int rg = 0; rg < 4; ++rg) {
      int brow = wm*16 + (lane >> 4)*4 + rg;
      sm.gates[brow][col] = acc[nf][rg];
    }
  }
  __syncthreads();

  // fused LSTM elementwise: tile holds i,f,g,o (16 units each) for 32 batch rows
  const float* bs0 = C.bias + (long)tn*BN;
  for (int e = tid; e < BM*UPT; e += 256) {
    int bl = e >> 4, ul = e & 15;
    float gi = sm.gates[bl][ 0 + ul] + bs0[ 0 + ul];
    float gf = sm.gates[bl][16 + ul] + bs0[16 + ul];
    float gg = sm.gates[bl][32 + ul] + bs0[32 + ul];
    float go = sm.gates[bl][48 + ul] + bs0[48 + ul];
    float iv = 1.f / (1.f + __expf(-gi));
    float fv = 1.f / (1.f + __expf(-gf));
    float gc = fminf(fmaxf(gg, -15.f), 15.f);
    float eg = __expf(2.f * gc);
    float gv = (eg - 1.f) / (eg + 1.f);
    float ov = 1.f / (1.f + __expf(-go));
    long ci = (long)(b0 + bl)*H_ + (long)tn*UPT + ul;
    float c2 = fv * C.c[ci] + iv * gv;
    C.c[ci] = c2;
    float cc = fminf(fmaxf(c2, -15.f), 15.f);
    float ec = __expf(2.f * cc);
    float th = (ec - 1.f) / (ec + 1.f);
    C.h[ci] = f2bf(ov * th);
  }
}

// ---------------- prep kernels ----------------
__global__ void k_convx(const float* x, unsigned short* xbf, long n) {
  long st = (long)gridDim.x * 256;
  for (long i = (long)blockIdx.x*256 + threadIdx.x; i < n; i += st) xbf[i] = f2bf(x[i]);
}

__global__ void k_init(const float* h0in, const float* c0in,
                       unsigned short* h0e0, unsigned short* h1e1,
                       float* c0buf, float* c1buf) {
  int i = blockIdx.x*256 + threadIdx.x;
  if (i < B_*H_) {
    h0e0[i] = f2bf(h0in[i]);
    h1e1[i] = f2bf(h0in[B_*H_ + i]);
    c0buf[i] = c0in[i];
    c1buf[i] = c0in[B_*H_ + i];
  }
}

// W_comb[3072][768] = dec_Wih0[3072][128] @ lin_W[128][768]  (f32)
__global__ __launch_bounds__(256) void k_wcomb(const float* A, const float* Bm, float* Cm) {
  __shared__ float sA[16*128];
  int tid = threadIdx.x;
  int r0 = blockIdx.x * 16;
  int c0 = blockIdx.y * 128;
  for (int e = tid; e < 16*128; e += 256)
    sA[e] = A[(long)(r0 + (e >> 7))*128 + (e & 127)];
  __syncthreads();
  int col = c0 + (tid & 127);
  int rg = (tid >> 7) * 8;
  float acc[8] = {0,0,0,0,0,0,0,0};
  for (int k = 0; k < 128; ++k) {
    float b = Bm[(long)k*768 + col];
#pragma unroll
    for (int r = 0; r < 8; ++r) acc[r] += sA[(rg + r)*128 + k] * b;
  }
  for (int r = 0; r < 8; ++r) Cm[(long)(r0 + rg + r)*768 + col] = acc[r];
}

__global__ void k_bcomb(const float* dWih0, const float* linb, const float* db0, float* bc) {
  int j = blockIdx.x*256 + threadIdx.x;
  if (j < NG) {
    float s = db0[j];
    for (int f = 0; f < 128; ++f) s += dWih0[(long)j*128 + f] * linb[f];
    bc[j] = s;
  }
}

// pack [src1|src2] into bf16, rows permuted so each 64-row tile = 4 gates x 16 units
__global__ void k_pack(unsigned short* dst, float* bdst, const float* s1, int K1,
                       const float* s2, int K2, const float* bs) {
  long Kt = K1 + K2, total = (long)NG * Kt;
  long st = (long)gridDim.x * 256;
  for (long i = (long)blockIdx.x*256 + threadIdx.x; i < total; i += st) {
    int n = (int)(i / Kt), k = (int)(i % Kt);
    int tn = n >> 6, r = n & 63;
    int j = (r >> 4)*H_ + tn*UPT + (r & 15);
    float v = (k < K1) ? s1[(long)j*K1 + k] : s2[(long)j*K2 + (k - K1)];
    dst[i] = f2bf(v);
    if (k == 0) bdst[n] = bs[j];
  }
}

// W_ext (3200x1536): rows<3072 = perm[W_comb|dec_Whh0] (bias b_comb);
// rows 3072.. = [lin_W|0] (bias lin_b)  -> emits y as extra output columns
__global__ void k_packext(unsigned short* dst, float* bdst, const float* wcomb,
                          const float* whh0, const float* bcomb,
                          const float* linW, const float* linb) {
  long total = (long)(NG + F_) * (2*H_);
  long st = (long)gridDim.x * 256;
  for (long i = (long)blockIdx.x*256 + threadIdx.x; i < total; i += st) {
    int n = (int)(i / (2*H_)), k = (int)(i % (2*H_));
    float v;
    if (n < NG) {
      int tn = n >> 6, r = n & 63;
      int j = (r >> 4)*H_ + tn*UPT + (r & 15);
      v = (k < H_) ? wcomb[(long)j*H_ + k] : whh0[(long)j*H_ + (k - H_)];
      if (k == 0) bdst[n] = bcomb[j];
    } else {
      int f = n - NG;
      v = (k < H_) ? linW[(long)f*H_ + k] : 0.f;
      if (k == 0) bdst[n] = linb[f];
    }
    dst[i] = f2bf(v);
  }
}

__global__ void k_packlin(unsigned short* dst, const float* linW) {
  int i = blockIdx.x*256 + threadIdx.x;
  if (i < F_*H_) dst[i] = f2bf(linW[i]);
}

// ---------------- host ----------------
extern "C" void kernel_launch(void* const* d_in, const int* in_sizes, int n_in,
                              void* d_out, int out_size, void* d_ws, size_t ws_size,
                              hipStream_t stream)
{
  (void)in_sizes; (void)n_in; (void)out_size; (void)ws_size;
  const float* x     = (const float*)d_in[0];
  const float* h0in  = (const float*)d_in[1];
  const float* c0in  = (const float*)d_in[2];
  const float* eWih0 = (const float*)d_in[3];
  const float* eWhh0 = (const float*)d_in[4];
  const float* eb0   = (const float*)d_in[5];
  const float* eWih1 = (const float*)d_in[6];
  const float* eWhh1 = (const float*)d_in[7];
  const float* eb1   = (const float*)d_in[8];
  const float* dWih0 = (const float*)d_in[9];
  const float* dWhh0 = (const float*)d_in[10];
  const float* db0   = (const float*)d_in[11];
  const float* dWih1 = (const float*)d_in[12];
  const float* dWhh1 = (const float*)d_in[13];
  const float* db1   = (const float*)d_in[14];
  const float* linW  = (const float*)d_in[15];
  const float* linb  = (const float*)d_in[16];
  float* out = (float*)d_out;

  char* wp = (char*)d_ws;
  auto alloc = [&](size_t bytes) -> void* {
    void* p = (void*)wp;
    wp += (bytes + 255) & ~(size_t)255;
    return p;
  };
  unsigned short* xbf    = (unsigned short*)alloc((size_t)B_*T_*F_*2);
  unsigned short* Wenc0  = (unsigned short*)alloc((size_t)NG*(F_+H_)*2);
  unsigned short* Wenc1  = (unsigned short*)alloc((size_t)NG*(2*H_)*2);
  unsigned short* Wdec0f = (unsigned short*)alloc((size_t)NG*(F_+H_)*2);
  unsigned short* Wext   = (unsigned short*)alloc((size_t)(NG+F_)*(2*H_)*2);
  unsigned short* Wdec1  = (unsigned short*)alloc((size_t)NG*(2*H_)*2);
  unsigned short* linWbf = (unsigned short*)alloc((size_t)F_*H_*2);
  float* Wcomb = (float*)alloc((size_t)NG*H_*4);
  float* benc0 = (float*)alloc((size_t)NG*4);
  float* benc1 = (float*)alloc((size_t)NG*4);
  float* bdec0f= (float*)alloc((size_t)NG*4);
  float* bext  = (float*)alloc((size_t)(NG+F_)*4);
  float* bdec1 = (float*)alloc((size_t)NG*4);
  float* bcomb = (float*)alloc((size_t)NG*4);
  unsigned short* h0e[2];
  h0e[0] = (unsigned short*)alloc((size_t)B_*H_*2);
  h0e[1] = (unsigned short*)alloc((size_t)B_*H_*2);
  unsigned short* h1e[2];
  h1e[0] = (unsigned short*)alloc((size_t)B_*H_*2);
  h1e[1] = (unsigned short*)alloc((size_t)B_*H_*2);
  float* c0buf = (float*)alloc((size_t)B_*H_*4);
  float* c1buf = (float*)alloc((size_t)B_*H_*4);

  // ---- prep
  k_convx<<<2048, 256, 0, stream>>>(x, xbf, (long)B_*T_*F_);
  k_init<<<(B_*H_+255)/256, 256, 0, stream>>>(h0in, c0in, h0e[0], h1e[1], c0buf, c1buf);
  k_wcomb<<<dim3(192,6), 256, 0, stream>>>(dWih0, linW, Wcomb);
  k_bcomb<<<(NG+255)/256, 256, 0, stream>>>(dWih0, linb, db0, bcomb);
  k_pack<<<2048, 256, 0, stream>>>(Wenc0, benc0, eWih0, F_, eWhh0, H_, eb0);
  k_pack<<<2048, 256, 0, stream>>>(Wenc1, benc1, eWih1, H_, eWhh1, H_, eb1);
  k_pack<<<2048, 256, 0, stream>>>(Wdec0f, bdec0f, dWih0, F_, dWhh0, H_, db0);
  k_pack<<<2048, 256, 0, stream>>>(Wdec1, bdec1, dWih1, H_, dWhh1, H_, db1);
  k_packext<<<2048, 256, 0, stream>>>(Wext, bext, Wcomb, dWhh0, bcomb, linW, linb);
  k_packlin<<<(F_*H_+255)/256, 256, 0, stream>>>(linWbf, linW);

  auto mk = [&](const unsigned short* A1, int lda1, int K1,
                const unsigned short* A2, int lda2, int K2,
                const unsigned short* W, const float* bias,
                float* c, unsigned short* h, float* yo, int yt,
                int N, int ngates) {
    Cell cc; cc.A1=A1; cc.lda1=lda1; cc.K1=K1; cc.A2=A2; cc.lda2=lda2; cc.K2=K2;
    cc.W=W; cc.ldw=K1+K2; cc.bias=bias; cc.c=c; cc.h=h; cc.yout=yo; cc.yt=yt;
    cc.N=N; cc.ngates=ngates;
    return cc;
  };

  // ---- encoder: stage s runs enc-layer0(t=s) and enc-layer1(t=s-1) in one launch
  for (int s = 0; s <= T_; ++s) {
    Cell cA = {}, cB = {};
    int na = 0, nb = 0;
    if (s < T_) {
      cA = mk(xbf + (long)s*F_, T_*F_, F_, h0e[s&1], H_, H_,
              Wenc0, benc0, c0buf, h0e[(s+1)&1], nullptr, 0, NG, NG);
      na = 192;
    }
    if (s >= 1) {
      cB = mk(h0e[s&1], H_, H_, h1e[s&1], H_, H_,
              Wenc1, benc1, c1buf, h1e[(s+1)&1], nullptr, 0, NG, NG);
      nb = 192;
    }
    if (na == 0) { cA = cB; na = nb; nb = 0; }
    cell_kernel<<<na+nb, 256, 0, stream>>>(cA, cB, na);
  }

  // ---- decoder: strictly serial (layer0(t+1) depends on layer1(t) via W_comb)
  {
    Cell c0 = mk(xbf + (long)(T_-1)*F_, T_*F_, F_, h0e[0], H_, H_,
                 Wdec0f, bdec0f, c0buf, h0e[1], nullptr, 0, NG, NG);
    cell_kernel<<<192, 256, 0, stream>>>(c0, c0, 192);
    Cell c1 = mk(h0e[1], H_, H_, h1e[1], H_, H_,
                 Wdec1, bdec1, c1buf, h1e[0], nullptr, 0, NG, NG);
    cell_kernel<<<192, 256, 0, stream>>>(c1, c1, 192);
  }
  for (int t = 1; t < T_; ++t) {
    // dec-layer0(t): A=[h1(t-1)|h0(t-1)] @ [W_comb|Whh0]  (+ y(t-1) side columns)
    Cell cd0 = mk(h1e[(t+1)&1], H_, H_, h0e[t&1], H_, H_,
                  Wext, bext, c0buf, h0e[(t+1)&1], out, T_-t, NG+F_, NG);
    cell_kernel<<<200, 256, 0, stream>>>(cd0, cd0, 200);
    // dec-layer1(t): A=[h0(t)|h1(t-1)]
    Cell cd1 = mk(h0e[(t+1)&1], H_, H_, h1e[(t+1)&1], H_, H_,
                  Wdec1, bdec1, c1buf, h1e[t&1], nullptr, 0, NG, NG);
    cell_kernel<<<192, 256, 0, stream>>>(cd1, cd1, 192);
  }
  {
    // final y(T-1) -> out[:,0,:]
    Cell cy = mk(h1e[1], H_, H_, h1e[1], H_, 0,
                 linWbf, linb, nullptr, nullptr, out, 0, F_, 0);
    cell_kernel<<<8, 256, 0, stream>>>(cy, cy, 8);
  }
}